// Round 4
// baseline (504.172 us; speedup 1.0000x reference)
//
#include <hip/hip_runtime.h>

// GIN 2-layer, N=100000, E=1600000, D=128.
// R4: slab-sliced activation layout (8 slabs x 16 cols, slab contiguous) +
// slab = blockIdx%8 -> XCD-local gather; per-XCD L2 working set 3.2MB < 4MB.
// CSR via bucket multisplit (R3). bf16 activations, MFMA fused MLP.

typedef __attribute__((ext_vector_type(8))) short bf16x8;
typedef __attribute__((ext_vector_type(4))) float floatx4;

#define WS_ALIGN(x) (((x) + 255) & ~(size_t)255)
#define NBMAX 400   // max buckets (n <= 102400)
#define BCAP 6144   // per-bucket capacity (mean 4096, sd ~64)

__device__ __forceinline__ unsigned short f2b(float f) {  // RTNE fp32->bf16
  unsigned u = __builtin_bit_cast(unsigned, f);
  u = (u + 0x7FFF + ((u >> 16) & 1)) >> 16;
  return (unsigned short)u;
}
__device__ __forceinline__ float b2f(unsigned u16) {  // low 16 bits = bf16
  return __builtin_bit_cast(float, u16 << 16);
}

// ---------- phase A: multisplit edges into 256-node buckets ----------
__global__ __launch_bounds__(256) void bucket_split(const int* __restrict__ src,
                                                    const int* __restrict__ dst,
                                                    int* __restrict__ bcnt,
                                                    unsigned* __restrict__ barr, int E, int nb) {
  __shared__ int cnt[NBMAX], base[NBMAX], cur[NBMAX];
  int t = threadIdx.x;
  for (int i = t; i < nb; i += 256) { cnt[i] = 0; cur[i] = 0; }
  __syncthreads();
  int e0 = blockIdx.x * 8192;
  int s[32], d[32];
#pragma unroll
  for (int k = 0; k < 32; k++) {
    int e = e0 + k * 256 + t;
    if (e < E) { s[k] = src[e]; d[k] = dst[e]; } else { d[k] = -1; }
  }
#pragma unroll
  for (int k = 0; k < 32; k++)
    if (d[k] >= 0) atomicAdd(&cnt[d[k] >> 8], 1);
  __syncthreads();
  for (int i = t; i < nb; i += 256) base[i] = cnt[i] ? atomicAdd(&bcnt[i], cnt[i]) : 0;
  __syncthreads();
#pragma unroll
  for (int k = 0; k < 32; k++)
    if (d[k] >= 0) {
      int b = d[k] >> 8;
      int r = atomicAdd(&cur[b], 1);
      barr[(size_t)b * BCAP + base[b] + r] = ((unsigned)(d[k] & 255) << 17) | (unsigned)s[k];
    }
}

// ---------- phase B: scan bucket counts ----------
__global__ void bucket_scan(const int* __restrict__ bcnt, int* __restrict__ sbase, int nb,
                            int* __restrict__ rowptr, int n) {
  __shared__ int buf[512];
  int t = threadIdx.x;
  int v = (t < nb) ? bcnt[t] : 0;
  buf[t] = v;
  __syncthreads();
  for (int off = 1; off < 512; off <<= 1) {
    int add = (t >= off) ? buf[t - off] : 0;
    __syncthreads();
    buf[t] += add;
    __syncthreads();
  }
  if (t < nb) sbase[t] = buf[t] - v;  // exclusive
  if (t == nb - 1) { sbase[nb] = buf[t]; rowptr[n] = buf[t]; }
}

// ---------- phase C: per-bucket CSR finalize ----------
__global__ __launch_bounds__(256) void bucket_csr(const unsigned* __restrict__ barr,
                                                  const int* __restrict__ bcnt,
                                                  const int* __restrict__ sbase,
                                                  int* __restrict__ rowptr, int* __restrict__ srt,
                                                  int n) {
  __shared__ int cnt[256], off[256], off2[256];
  int b = blockIdx.x, t = threadIdx.x;
  int cb = bcnt[b];
  int node0 = b * 256;
  int nlocal = min(256, n - node0);
  cnt[t] = 0;
  off2[t] = 0;
  __syncthreads();
  const unsigned* bp = barr + (size_t)b * BCAP;
  for (int i = t; i < cb; i += 256) atomicAdd(&cnt[bp[i] >> 17], 1);
  __syncthreads();
  int v = cnt[t];
  off[t] = v;
  __syncthreads();
  for (int o = 1; o < 256; o <<= 1) {
    int add = (t >= o) ? off[t - o] : 0;
    __syncthreads();
    off[t] += add;
    __syncthreads();
  }
  int excl = off[t] - v;
  int sb = sbase[b];
  if (t < nlocal) rowptr[node0 + t] = sb + excl;
  cnt[t] = excl;
  __syncthreads();
  for (int i = t; i < cb; i += 256) {
    unsigned pk = bp[i];
    int local = pk >> 17;
    int r = atomicAdd(&off2[local], 1);
    srt[sb + cnt[local] + r] = pk & 0x1FFFF;
  }
}

// ---------- fp32 row-major -> bf16 sliced ----------
// sliced layout (uints): buf[s*n8 + node*8 + c], s in [0,8), c in [0,8)
// (slab s holds cols [s*16, s*16+16) as 8 uints per node; slab contiguous)
__global__ void cvt_sliced(const float* __restrict__ x, unsigned* __restrict__ xb, int n, int n8) {
  int t = threadIdx.x;
  int uidx = blockIdx.x * 256 + t;  // in [0, n*8)
  if (uidx >= n8) return;
  int s = blockIdx.y;
  int node = uidx >> 3, c = uidx & 7;
  float2 v = ((const float2*)x)[(size_t)node * 64 + s * 8 + c];
  xb[(size_t)s * n8 + uidx] = (unsigned)f2b(v.x) | ((unsigned)f2b(v.y) << 16);
}

// ---------- aggregation, sliced (bf16 in/out, fp32 accumulate) ----------
// block: 32 nodes x 8 uint-cols of one slab; slab = blockIdx%8 -> XCD-local.
__global__ __launch_bounds__(256) void aggregate_sliced(const unsigned* __restrict__ X,
                                                        const int* __restrict__ rowptr,
                                                        const int* __restrict__ srt,
                                                        unsigned* __restrict__ out, int n,
                                                        int n8) {
  int s = blockIdx.x & 7;
  int tile = blockIdx.x >> 3;
  int t = threadIdx.x;
  int node = tile * 32 + (t >> 3);
  if (node >= n) return;
  int c = t & 7;
  const unsigned* Xs = X + (size_t)s * n8;
  unsigned u = Xs[node * 8 + c];
  float ax = b2f(u & 0xffff), ay = b2f(u >> 16);
  int p = rowptr[node], e = rowptr[node + 1];
  for (; p + 4 <= e; p += 4) {
    int s0 = __builtin_nontemporal_load(&srt[p]);
    int s1 = __builtin_nontemporal_load(&srt[p + 1]);
    int s2 = __builtin_nontemporal_load(&srt[p + 2]);
    int s3 = __builtin_nontemporal_load(&srt[p + 3]);
    unsigned u0 = Xs[s0 * 8 + c];
    unsigned u1 = Xs[s1 * 8 + c];
    unsigned u2 = Xs[s2 * 8 + c];
    unsigned u3 = Xs[s3 * 8 + c];
    ax += b2f(u0 & 0xffff) + b2f(u1 & 0xffff) + b2f(u2 & 0xffff) + b2f(u3 & 0xffff);
    ay += b2f(u0 >> 16) + b2f(u1 >> 16) + b2f(u2 >> 16) + b2f(u3 >> 16);
  }
  for (; p < e; ++p) {
    unsigned uu = Xs[__builtin_nontemporal_load(&srt[p]) * 8 + c];
    ax += b2f(uu & 0xffff);
    ay += b2f(uu >> 16);
  }
  out[(size_t)s * n8 + node * 8 + c] = (unsigned)f2b(ax) | ((unsigned)f2b(ay) << 16);
}

// ---------- fused MLP: C = (relu(A@Wa^T+ba)) @ Wb^T + bb ----------
// A in sliced bf16 layout; OUT_SLICED=1 -> sliced bf16 out, else fp32 row-major.
__device__ __forceinline__ void stage_w(char* buf, const float* __restrict__ W, int t) {
  for (int idx = t; idx < 2048; idx += 512) {  // idx = 16B-chunk id (8 bf16)
    int nrow = idx >> 4, c = idx & 15;
    float4 a = ((const float4*)W)[idx * 2];
    float4 b = ((const float4*)W)[idx * 2 + 1];
    uint4 pk;
    pk.x = (unsigned)f2b(a.x) | ((unsigned)f2b(a.y) << 16);
    pk.y = (unsigned)f2b(a.z) | ((unsigned)f2b(a.w) << 16);
    pk.z = (unsigned)f2b(b.x) | ((unsigned)f2b(b.y) << 16);
    pk.w = (unsigned)f2b(b.z) | ((unsigned)f2b(b.w) << 16);
    *(uint4*)(buf + nrow * 256 + ((c ^ (nrow & 15)) << 4)) = pk;
  }
}

template <int OUT_SLICED>
__global__ __launch_bounds__(512) void mlp_kernel(
    const unsigned* __restrict__ A, const float* __restrict__ Wa,
    const float* __restrict__ ba, const float* __restrict__ Wb,
    const float* __restrict__ bb, void* __restrict__ Cout, int n, int n8) {
  __shared__ __align__(16) char lds[65536];
  char* bufA = lds;          // Wa, later h
  char* bufB = lds + 32768;  // Wb
  int t = threadIdx.x;
  stage_w(bufA, Wa, t);
  stage_w(bufB, Wb, t);

  int wave = t >> 6, lane = t & 63;
  int m = lane & 15, q = lane >> 4;
  int rbase = blockIdx.x * 128;
  int rowA = rbase + wave * 16 + m;
  int rA = rowA < n ? rowA : (n - 1);

  // A-frag ks: cols [ks*32+q*8, +8) -> slab ks*2+(q>>1), uint off (q&1)*4
  bf16x8 af[4];
#pragma unroll
  for (int ks = 0; ks < 4; ks++)
    af[ks] = *(const bf16x8*)(A + (size_t)(ks * 2 + (q >> 1)) * n8 + rA * 8 + (q & 1) * 4);

  __syncthreads();

  floatx4 acc[8];
  floatx4 zf = {0.f, 0.f, 0.f, 0.f};
#pragma unroll
  for (int j = 0; j < 8; j++) acc[j] = zf;
#pragma unroll
  for (int ks = 0; ks < 4; ks++) {
#pragma unroll
    for (int j = 0; j < 8; j++) {
      bf16x8 bf = *(const bf16x8*)(bufA + (j * 16 + m) * 256 + (((ks * 4 + q) ^ m) << 4));
      acc[j] = __builtin_amdgcn_mfma_f32_16x16x32_bf16(af[ks], bf, acc[j], 0, 0, 0);
    }
  }
  __syncthreads();

#pragma unroll
  for (int j = 0; j < 8; j++) {
    float bias = ba[j * 16 + m];
#pragma unroll
    for (int reg = 0; reg < 4; reg++) {
      float v = fmaxf(acc[j][reg] + bias, 0.f);
      int lr = wave * 16 + q * 4 + reg;
      int col = j * 16 + m;
      *(unsigned short*)(bufA + lr * 256 + (((col >> 3) ^ (lr & 15)) << 4) + (col & 7) * 2) =
          f2b(v);
    }
  }
  __syncthreads();

  int lrA = wave * 16 + m;
#pragma unroll
  for (int ks = 0; ks < 4; ks++)
    af[ks] = *(const bf16x8*)(bufA + lrA * 256 + (((ks * 4 + q) ^ m) << 4));
#pragma unroll
  for (int j = 0; j < 8; j++) acc[j] = zf;
#pragma unroll
  for (int ks = 0; ks < 4; ks++) {
#pragma unroll
    for (int j = 0; j < 8; j++) {
      bf16x8 bf = *(const bf16x8*)(bufB + (j * 16 + m) * 256 + (((ks * 4 + q) ^ m) << 4));
      acc[j] = __builtin_amdgcn_mfma_f32_16x16x32_bf16(af[ks], bf, acc[j], 0, 0, 0);
    }
  }

#pragma unroll
  for (int j = 0; j < 8; j++) {
    float bias = bb[j * 16 + m];
#pragma unroll
    for (int reg = 0; reg < 4; reg++) {
      int row = rbase + wave * 16 + q * 4 + reg;
      if (row >= n) continue;
      float v = acc[j][reg] + bias;
      if (OUT_SLICED) {
        // col = j*16+m -> slab j, short index row*16+m
        ((unsigned short*)((unsigned*)Cout + (size_t)j * n8))[row * 16 + m] = f2b(v);
      } else {
        ((float*)Cout)[(size_t)row * 128 + j * 16 + m] = v;
      }
    }
  }
}

extern "C" void kernel_launch(void* const* d_in, const int* in_sizes, int n_in,
                              void* d_out, int out_size, void* d_ws, size_t ws_size,
                              hipStream_t stream) {
  const float* x   = (const float*)d_in[0];
  const int*   ei  = (const int*)d_in[1];
  const float* w0a = (const float*)d_in[2];
  const float* b0a = (const float*)d_in[3];
  const float* w0b = (const float*)d_in[4];
  const float* b0b = (const float*)d_in[5];
  const float* w1a = (const float*)d_in[6];
  const float* b1a = (const float*)d_in[7];
  const float* w1b = (const float*)d_in[8];
  const float* b1b = (const float*)d_in[9];
  float* out = (float*)d_out;

  int n = in_sizes[0] / 128;  // 100000
  int E = in_sizes[1] / 2;    // 1600000
  const int* src = ei;
  const int* dst = ei + E;
  int nb = (n + 255) / 256;  // 391
  int n8 = n * 8;            // uints per slab

  char* w = (char*)d_ws;
  int* rowptr = (int*)w;           w += WS_ALIGN((size_t)(n + 1) * 4);
  int* sbase = (int*)w;            w += WS_ALIGN((size_t)(NBMAX + 1) * 4);
  int* bcnt = (int*)w;             w += WS_ALIGN((size_t)NBMAX * 4);
  int* srt = (int*)w;              w += WS_ALIGN((size_t)E * 4);
  unsigned* xb = (unsigned*)w;     w += WS_ALIGN((size_t)n * 128 * 2);
  // barr (nb*BCAP uints, ~9.6MB) overlaps B1: barr is dead before the first
  // aggregate writes B1.
  unsigned* barr = (unsigned*)w;
  unsigned* B1 = (unsigned*)w;

  // ---- CSR build (hierarchical) ----
  hipMemsetAsync(bcnt, 0, (size_t)nb * 4, stream);
  bucket_split<<<(E + 8191) / 8192, 256, 0, stream>>>(src, dst, bcnt, barr, E, nb);
  bucket_scan<<<1, 512, 0, stream>>>(bcnt, sbase, nb, rowptr, n);
  bucket_csr<<<nb, 256, 0, stream>>>(barr, bcnt, sbase, rowptr, srt, n);

  // ---- x -> bf16 sliced ----
  dim3 cgrid((n8 + 255) / 256, 8);
  cvt_sliced<<<cgrid, 256, 0, stream>>>(x, xb, n, n8);

  int agg_grid = ((n + 31) / 32) * 8;
  int mlp_grid = (n + 127) / 128;

  // ---- layer 1 ----  (xb -> B1 -> xb)
  aggregate_sliced<<<agg_grid, 256, 0, stream>>>(xb, rowptr, srt, B1, n, n8);
  mlp_kernel<1><<<mlp_grid, 512, 0, stream>>>(B1, w0a, b0a, w0b, b0b, xb, n, n8);

  // ---- layer 2 ----  (xb -> B1 -> out)
  aggregate_sliced<<<agg_grid, 256, 0, stream>>>(xb, rowptr, srt, B1, n, n8);
  mlp_kernel<0><<<mlp_grid, 512, 0, stream>>>(B1, w1a, b1a, w1b, b1b, out, n, n8);
}

// Round 5
// 333.549 us; speedup vs baseline: 1.5115x; 1.5115x over previous
//
#include <hip/hip_runtime.h>

// GIN 2-layer, N=100000, E=1600000, D=128.
// R5: revert R4 slicing (issue-bound regression). Gather restructured for
// latency: lane=(slot s, chunk c), dwordx4 per lane -> 4 edges / 1KB per
// VMEM instruction, wave-uniform trip count, shfl_xor slot reduction.

typedef __attribute__((ext_vector_type(8))) short bf16x8;
typedef __attribute__((ext_vector_type(4))) float floatx4;

#define WS_ALIGN(x) (((x) + 255) & ~(size_t)255)
#define NBMAX 400   // max buckets (n <= 102400)
#define BCAP 6144   // per-bucket capacity (mean 4096, sd ~64)

__device__ __forceinline__ unsigned short f2b(float f) {  // RTNE fp32->bf16
  unsigned u = __builtin_bit_cast(unsigned, f);
  u = (u + 0x7FFF + ((u >> 16) & 1)) >> 16;
  return (unsigned short)u;
}
__device__ __forceinline__ float b2f(unsigned u16) {  // low 16 bits = bf16
  return __builtin_bit_cast(float, u16 << 16);
}

// ---------- phase A: multisplit edges into 256-node buckets ----------
__global__ __launch_bounds__(256) void bucket_split(const int* __restrict__ src,
                                                    const int* __restrict__ dst,
                                                    int* __restrict__ bcnt,
                                                    unsigned* __restrict__ barr, int E, int nb) {
  __shared__ int cnt[NBMAX], base[NBMAX], cur[NBMAX];
  int t = threadIdx.x;
  for (int i = t; i < nb; i += 256) { cnt[i] = 0; cur[i] = 0; }
  __syncthreads();
  int e0 = blockIdx.x * 8192;
  int s[32], d[32];
#pragma unroll
  for (int k = 0; k < 32; k++) {
    int e = e0 + k * 256 + t;
    if (e < E) { s[k] = src[e]; d[k] = dst[e]; } else { d[k] = -1; }
  }
#pragma unroll
  for (int k = 0; k < 32; k++)
    if (d[k] >= 0) atomicAdd(&cnt[d[k] >> 8], 1);
  __syncthreads();
  for (int i = t; i < nb; i += 256) base[i] = cnt[i] ? atomicAdd(&bcnt[i], cnt[i]) : 0;
  __syncthreads();
#pragma unroll
  for (int k = 0; k < 32; k++)
    if (d[k] >= 0) {
      int b = d[k] >> 8;
      int r = atomicAdd(&cur[b], 1);
      barr[(size_t)b * BCAP + base[b] + r] = ((unsigned)(d[k] & 255) << 17) | (unsigned)s[k];
    }
}

// ---------- phase B: scan bucket counts ----------
__global__ void bucket_scan(const int* __restrict__ bcnt, int* __restrict__ sbase, int nb,
                            int* __restrict__ rowptr, int n) {
  __shared__ int buf[512];
  int t = threadIdx.x;
  int v = (t < nb) ? bcnt[t] : 0;
  buf[t] = v;
  __syncthreads();
  for (int off = 1; off < 512; off <<= 1) {
    int add = (t >= off) ? buf[t - off] : 0;
    __syncthreads();
    buf[t] += add;
    __syncthreads();
  }
  if (t < nb) sbase[t] = buf[t] - v;  // exclusive
  if (t == nb - 1) { sbase[nb] = buf[t]; rowptr[n] = buf[t]; }
}

// ---------- phase C: per-bucket CSR finalize ----------
__global__ __launch_bounds__(256) void bucket_csr(const unsigned* __restrict__ barr,
                                                  const int* __restrict__ bcnt,
                                                  const int* __restrict__ sbase,
                                                  int* __restrict__ rowptr, int* __restrict__ srt,
                                                  int n) {
  __shared__ int cnt[256], off[256], off2[256];
  int b = blockIdx.x, t = threadIdx.x;
  int cb = bcnt[b];
  int node0 = b * 256;
  int nlocal = min(256, n - node0);
  cnt[t] = 0;
  off2[t] = 0;
  __syncthreads();
  const unsigned* bp = barr + (size_t)b * BCAP;
  for (int i = t; i < cb; i += 256) atomicAdd(&cnt[bp[i] >> 17], 1);
  __syncthreads();
  int v = cnt[t];
  off[t] = v;
  __syncthreads();
  for (int o = 1; o < 256; o <<= 1) {
    int add = (t >= o) ? off[t - o] : 0;
    __syncthreads();
    off[t] += add;
    __syncthreads();
  }
  int excl = off[t] - v;
  int sb = sbase[b];
  if (t < nlocal) rowptr[node0 + t] = sb + excl;
  cnt[t] = excl;
  __syncthreads();
  for (int i = t; i < cb; i += 256) {
    unsigned pk = bp[i];
    int local = pk >> 17;
    int r = atomicAdd(&off2[local], 1);
    srt[sb + cnt[local] + r] = pk & 0x1FFFF;
  }
}

// ---------- fp32 -> bf16 convert (row-major) ----------
__global__ void cvt_kernel(const float* __restrict__ x, unsigned short* __restrict__ xb, int n4) {
  int i = blockIdx.x * blockDim.x + threadIdx.x;
  if (i < n4) {
    float4 v = ((const float4*)x)[i];
    uint2 pk;
    pk.x = (unsigned)f2b(v.x) | ((unsigned)f2b(v.y) << 16);
    pk.y = (unsigned)f2b(v.z) | ((unsigned)f2b(v.w) << 16);
    ((uint2*)xb)[i] = pk;
  }
}

// ---------- aggregation (bf16 in/out, fp32 accumulate) ----------
// one wave per node. lane = (s<<4)|c: s = edge slot (0..3), c = 16B chunk
// (0..15). One VMEM instruction gathers 4 edges x 256B. Trip count is
// wave-uniform; tail lanes zero their load via cndmask. Slot reduction via
// 2 shfl_xor rounds; packed coalesced 256B store.
__global__ __launch_bounds__(256) void aggregate_bf16(const unsigned short* __restrict__ X,
                                                      const int* __restrict__ rowptr,
                                                      const int* __restrict__ srt,
                                                      unsigned short* __restrict__ out, int n) {
  int w = blockIdx.x * 4 + (threadIdx.x >> 6);
  if (w >= n) return;
  int lane = threadIdx.x & 63;
  int c = lane & 15;  // 16B chunk within row
  int s = lane >> 4;  // edge slot
  const uint4* Xv = (const uint4*)X;  // 16 uint4 per row

  float acc[8];
#pragma unroll
  for (int i = 0; i < 8; i++) acc[i] = 0.f;

  // self row: slot 0 only
  if (s == 0) {
    uint4 u = Xv[(size_t)w * 16 + c];
    acc[0] += b2f(u.x & 0xffff); acc[1] += b2f(u.x >> 16);
    acc[2] += b2f(u.y & 0xffff); acc[3] += b2f(u.y >> 16);
    acc[4] += b2f(u.z & 0xffff); acc[5] += b2f(u.z >> 16);
    acc[6] += b2f(u.w & 0xffff); acc[7] += b2f(u.w >> 16);
  }

  int p0 = rowptr[w], e = rowptr[w + 1];
  int trips = (e - p0 + 3) >> 2;
  int idx = p0 + s;
#pragma unroll 2
  for (int i = 0; i < trips; i++, idx += 4) {
    bool valid = idx < e;
    int r = srt[valid ? idx : (e - 1)];
    uint4 u = Xv[(size_t)r * 16 + c];
    if (!valid) { u.x = 0; u.y = 0; u.z = 0; u.w = 0; }
    acc[0] += b2f(u.x & 0xffff); acc[1] += b2f(u.x >> 16);
    acc[2] += b2f(u.y & 0xffff); acc[3] += b2f(u.y >> 16);
    acc[4] += b2f(u.z & 0xffff); acc[5] += b2f(u.z >> 16);
    acc[6] += b2f(u.w & 0xffff); acc[7] += b2f(u.w >> 16);
  }

  // reduce across slots (lane bits 4,5)
#pragma unroll
  for (int i = 0; i < 8; i++) {
    acc[i] += __shfl_xor(acc[i], 16, 64);
    acc[i] += __shfl_xor(acc[i], 32, 64);
  }

  // lane (c,s) writes uint c*4+s = cols (c*8+2s, c*8+2s+1)
  unsigned pk = (unsigned)f2b(acc[2 * s]) | ((unsigned)f2b(acc[2 * s + 1]) << 16);
  ((unsigned*)out)[(size_t)w * 64 + c * 4 + s] = pk;
}

// ---------- fused MLP: C = (relu(A@Wa^T+ba)) @ Wb^T + bb ----------
__device__ __forceinline__ void stage_w(char* buf, const float* __restrict__ W, int t) {
  for (int idx = t; idx < 2048; idx += 512) {  // idx = 16B-chunk id (8 bf16)
    int nrow = idx >> 4, c = idx & 15;
    float4 a = ((const float4*)W)[idx * 2];
    float4 b = ((const float4*)W)[idx * 2 + 1];
    uint4 pk;
    pk.x = (unsigned)f2b(a.x) | ((unsigned)f2b(a.y) << 16);
    pk.y = (unsigned)f2b(a.z) | ((unsigned)f2b(a.w) << 16);
    pk.z = (unsigned)f2b(b.x) | ((unsigned)f2b(b.y) << 16);
    pk.w = (unsigned)f2b(b.z) | ((unsigned)f2b(b.w) << 16);
    *(uint4*)(buf + nrow * 256 + ((c ^ (nrow & 15)) << 4)) = pk;
  }
}

template <int OUT_BF16>
__global__ __launch_bounds__(512) void mlp_kernel(
    const unsigned short* __restrict__ A, const float* __restrict__ Wa,
    const float* __restrict__ ba, const float* __restrict__ Wb,
    const float* __restrict__ bb, void* __restrict__ Cout, int n) {
  __shared__ __align__(16) char lds[65536];
  char* bufA = lds;          // Wa, later h
  char* bufB = lds + 32768;  // Wb
  int t = threadIdx.x;
  stage_w(bufA, Wa, t);
  stage_w(bufB, Wb, t);

  int wave = t >> 6, lane = t & 63;
  int m = lane & 15, q = lane >> 4;
  int rbase = blockIdx.x * 128;
  int rowA = rbase + wave * 16 + m;
  int rA = rowA < n ? rowA : (n - 1);

  bf16x8 af[4];
  const bf16x8* Arow = (const bf16x8*)(A + (size_t)rA * 128);
#pragma unroll
  for (int ks = 0; ks < 4; ks++) af[ks] = Arow[ks * 4 + q];

  __syncthreads();

  floatx4 acc[8];
  floatx4 zf = {0.f, 0.f, 0.f, 0.f};
#pragma unroll
  for (int j = 0; j < 8; j++) acc[j] = zf;
#pragma unroll
  for (int ks = 0; ks < 4; ks++) {
#pragma unroll
    for (int j = 0; j < 8; j++) {
      bf16x8 bf = *(const bf16x8*)(bufA + (j * 16 + m) * 256 + (((ks * 4 + q) ^ m) << 4));
      acc[j] = __builtin_amdgcn_mfma_f32_16x16x32_bf16(af[ks], bf, acc[j], 0, 0, 0);
    }
  }
  __syncthreads();

#pragma unroll
  for (int j = 0; j < 8; j++) {
    float bias = ba[j * 16 + m];
#pragma unroll
    for (int reg = 0; reg < 4; reg++) {
      float v = fmaxf(acc[j][reg] + bias, 0.f);
      int lr = wave * 16 + q * 4 + reg;
      int col = j * 16 + m;
      *(unsigned short*)(bufA + lr * 256 + (((col >> 3) ^ (lr & 15)) << 4) + (col & 7) * 2) =
          f2b(v);
    }
  }
  __syncthreads();

  int lrA = wave * 16 + m;
#pragma unroll
  for (int ks = 0; ks < 4; ks++)
    af[ks] = *(const bf16x8*)(bufA + lrA * 256 + (((ks * 4 + q) ^ m) << 4));
#pragma unroll
  for (int j = 0; j < 8; j++) acc[j] = zf;
#pragma unroll
  for (int ks = 0; ks < 4; ks++) {
#pragma unroll
    for (int j = 0; j < 8; j++) {
      bf16x8 bf = *(const bf16x8*)(bufB + (j * 16 + m) * 256 + (((ks * 4 + q) ^ m) << 4));
      acc[j] = __builtin_amdgcn_mfma_f32_16x16x32_bf16(af[ks], bf, acc[j], 0, 0, 0);
    }
  }

#pragma unroll
  for (int j = 0; j < 8; j++) {
    float bias = bb[j * 16 + m];
#pragma unroll
    for (int reg = 0; reg < 4; reg++) {
      int row = rbase + wave * 16 + q * 4 + reg;
      if (row >= n) continue;
      float v = acc[j][reg] + bias;
      int col = j * 16 + m;
      if (OUT_BF16)
        ((unsigned short*)Cout)[(size_t)row * 128 + col] = f2b(v);
      else
        ((float*)Cout)[(size_t)row * 128 + col] = v;
    }
  }
}

extern "C" void kernel_launch(void* const* d_in, const int* in_sizes, int n_in,
                              void* d_out, int out_size, void* d_ws, size_t ws_size,
                              hipStream_t stream) {
  const float* x   = (const float*)d_in[0];
  const int*   ei  = (const int*)d_in[1];
  const float* w0a = (const float*)d_in[2];
  const float* b0a = (const float*)d_in[3];
  const float* w0b = (const float*)d_in[4];
  const float* b0b = (const float*)d_in[5];
  const float* w1a = (const float*)d_in[6];
  const float* b1a = (const float*)d_in[7];
  const float* w1b = (const float*)d_in[8];
  const float* b1b = (const float*)d_in[9];
  float* out = (float*)d_out;

  int n = in_sizes[0] / 128;  // 100000
  int E = in_sizes[1] / 2;    // 1600000
  const int* src = ei;
  const int* dst = ei + E;
  int nb = (n + 255) / 256;  // 391

  char* w = (char*)d_ws;
  int* rowptr = (int*)w;           w += WS_ALIGN((size_t)(n + 1) * 4);
  int* sbase = (int*)w;            w += WS_ALIGN((size_t)(NBMAX + 1) * 4);
  int* bcnt = (int*)w;             w += WS_ALIGN((size_t)NBMAX * 4);
  int* srt = (int*)w;              w += WS_ALIGN((size_t)E * 4);
  unsigned short* xb = (unsigned short*)w;  w += WS_ALIGN((size_t)n * 128 * 2);
  // barr (nb*BCAP uints, ~9.6MB) overlaps B1: barr is dead before the first
  // aggregate writes B1.
  unsigned* barr = (unsigned*)w;
  unsigned short* B1 = (unsigned short*)w;

  // ---- CSR build (hierarchical) ----
  hipMemsetAsync(bcnt, 0, (size_t)nb * 4, stream);
  bucket_split<<<(E + 8191) / 8192, 256, 0, stream>>>(src, dst, bcnt, barr, E, nb);
  bucket_scan<<<1, 512, 0, stream>>>(bcnt, sbase, nb, rowptr, n);
  bucket_csr<<<nb, 256, 0, stream>>>(barr, bcnt, sbase, rowptr, srt, n);

  // ---- x -> bf16 ----
  cvt_kernel<<<(n * 32 + 255) / 256, 256, 0, stream>>>(x, xb, n * 32);

  int agg_grid = (n + 3) / 4;
  int mlp_grid = (n + 127) / 128;

  // ---- layer 1 ----  (xb -> B1 -> xb)
  aggregate_bf16<<<agg_grid, 256, 0, stream>>>(xb, rowptr, srt, B1, n);
  mlp_kernel<1><<<mlp_grid, 512, 0, stream>>>(B1, w0a, b0a, w0b, b0b, xb, n);

  // ---- layer 2 ----  (xb -> B1 -> out)
  aggregate_bf16<<<agg_grid, 256, 0, stream>>>(xb, rowptr, srt, B1, n);
  mlp_kernel<0><<<mlp_grid, 512, 0, stream>>>(B1, w1a, b1a, w1b, b1b, out, n);
}